// Round 10
// baseline (221.163 us; speedup 1.0000x reference)
//
#include <hip/hip_runtime.h>
#include <hip/hip_bf16.h>

// Problem constants
#define B_   8
#define D1_  1024
#define DJ_  512
#define S_   2048
#define OUT_ 2048
#define IN_  2048          // D1 + 2*DJ
#define M_TOT (B_ * S_)    // 16384

typedef __attribute__((ext_vector_type(8))) short          bf16x8;
typedef __attribute__((ext_vector_type(8))) unsigned short ushort8;
typedef __attribute__((ext_vector_type(4))) float          f32x4;

typedef __attribute__((address_space(3))) unsigned int as3_uint;
typedef __attribute__((address_space(1))) unsigned int as1_uint;
typedef __attribute__((address_space(1))) float         as1_float;

__device__ __forceinline__ unsigned short f2bf(float f) {
    union { float f; unsigned u; } v; v.f = f;
    unsigned r = v.u + 0x7FFF + ((v.u >> 16) & 1);   // round-to-nearest-even
    return (unsigned short)(r >> 16);
}

__device__ __forceinline__ void gload_lds16(const void* g, const void* l) {
    __builtin_amdgcn_global_load_lds(
        (const as1_uint*)(unsigned long long)g,
        (as3_uint*)(unsigned int)(unsigned long long)l,
        16, 0, 0);
}

// ---------------------------------------------------------------------------
// Kernel 1: W f32 -> bf16 (only prep left; A transpose is fused into the GEMM)
__global__ __launch_bounds__(256) void convert_w_kernel(
        const float* __restrict__ W, unsigned short* __restrict__ Wb) {
    size_t i = (size_t)blockIdx.x * 256 + threadIdx.x;
    const float4* p = reinterpret_cast<const float4*>(W) + i * 2;
    float4 a = p[0], c = p[1];
    ushort8 h;
    h[0] = f2bf(a.x); h[1] = f2bf(a.y); h[2] = f2bf(a.z); h[3] = f2bf(a.w);
    h[4] = f2bf(c.x); h[5] = f2bf(c.y); h[6] = f2bf(c.z); h[7] = f2bf(c.w);
    *(reinterpret_cast<ushort8*>(Wb) + i) = h;
}

// ---------------------------------------------------------------------------
// Kernel 2: 256x256 bf16 GEMM, FUSED A concat+transpose+cvt (round 10).
// = round-7 GEMM core (proven 125.7us) + r8's AU staging (proven mapping,
// 0 bank conflicts) re-scheduled with >=2-burst fence slack per unit.
// C[M,N] = A[M,K]*B[N,K]^T + bias; A read from f32 [b][f][s] inputs directly.
// 512 thr = 8 waves (2M x 4N).  LDS As_/Bs_ [2buf][2 region][128][64] = 128 KiB.
// T2 swizzle on both: 16B slot c at c^(row&7).
//
// Per SP (compute K-tile t from buf p; stage t+1 -> p^1; ONE barrier):
//   units u=0..3: idx=wave*4+u, fg=idx&7 (f-chunk = k-slot), s=((idx>>3)<<6)+lane.
//   u0@top, u1@after-burst1, u2@mid2, u3@mid3 (u2/u3 reuse u0/u1 regs).
//   B: 4 gload_lds at top (full-SP slack).
//   vmcnt ledger (in-order): [u0_8,B_4]+u1 -> VMN(12)=>u0 | +u2 -> VMN(8)=>B,u1
//     | +u3 -> VMN(0)=>u2,u3.  Slack: u0/u1/u2 ~2 bursts (~1100cy), u3 ~1 burst
//     (~600cy, inputs L3-resident ~450cy), B full SP.  Writes drained by the
//     trailing lgkmcnt(0)+barrier (cross-wave visibility via barrier).
//   WAR: all stages target p^1, last read before previous SP's barrier.

__global__ __launch_bounds__(512, 2) void gemm256_kernel(
        const float* __restrict__ in1, const float* __restrict__ in2a,
        const float* __restrict__ in2b,
        const unsigned short* __restrict__ Bm,   // Wb [OUT_][IN_] bf16
        const float* __restrict__ bias,
        float* __restrict__ C) {
    __shared__ unsigned short As_[32768];   // [2][2][128][64]
    __shared__ unsigned short Bs_[32768];

    int bid = blockIdx.x;
    // XCD swizzle (r7): nwg = 512 = 8*64, bijective
    int swz = (bid & 7) * 64 + (bid >> 3);
    int m0 = (swz >> 3) * 256;
    int n0 = (swz & 7) * 256;

    int t = threadIdx.x;
    int lane = t & 63, wave = t >> 6;
    int wm = wave >> 2;
    int wn = wave & 3;
    int fr = lane & 15;
    int fkslot = lane >> 4;

    // B staging constants
    int sr  = t >> 3;
    int sc  = t & 7;
    int swc = sc ^ (sr & 7);

    // fragment read offsets
    int sl0 = ((fkslot)     ^ (fr & 7)) * 8;
    int sl1 = ((4 + fkslot) ^ (fr & 7)) * 8;
    int arow = wm * 64 + fr;
    int brow = wn * 32 + fr;

    // A-source: GEMM row m = b_idx*2048 + s
    int b_idx = m0 >> 11;
    int s0g   = m0 & 2047;
    const size_t sb1 = (size_t)b_idx * D1_ * S_;
    const size_t sb2 = (size_t)b_idx * DJ_ * S_;

#define ABASE(ktn_) ((ktn_) < 1024 \
        ? in1 + sb1 + (size_t)(ktn_) * S_ + s0g \
        : ((ktn_) < 1536 \
            ? in2a + sb2 + (size_t)((ktn_) - 1024) * S_ + s0g \
            : in2b + sb2 + (size_t)((ktn_) - 1536) * S_ + s0g))

// 8 coalesced global dword loads (AS1-cast so no flat_load touches lgkmcnt)
#define AU_LOAD(REG, u) do { \
    int _idx = wave * 4 + (u); int _fg = _idx & 7; \
    int _so = ((_idx >> 3) << 6) + lane; \
    const as1_float* _p = (const as1_float*)(unsigned long long)ab2; \
    _Pragma("unroll") \
    for (int _k = 0; _k < 8; ++_k) \
        REG[_k] = _p[(size_t)(_fg * 8 + _k) * S_ + _so]; \
} while (0)

// cvt + one swizzled ds_write_b128 (r8-verified mapping, 0 conflicts)
#define AU_CW(REG, u, bbn) do { \
    int _idx = wave * 4 + (u); int _fg = _idx & 7; \
    int _g = ((_idx >> 3) << 6) + lane; \
    int _qm = (_g >> 6) & 1; int _lr = ((_g >> 7) << 6) | (_g & 63); \
    ushort8 _h; \
    _Pragma("unroll") \
    for (int _k = 0; _k < 8; ++_k) _h[_k] = f2bf(REG[_k]); \
    *reinterpret_cast<ushort8*>( \
        As_ + ((bbn)*2 + _qm)*8192 + _lr*64 + (_fg ^ (_lr & 7))*8) = _h; \
} while (0)

#define STAGE_B(bb, h, kt) do { \
    const unsigned short* _g0 = Bm + (size_t)(n0 + (sr>>5)*64 + (h)*32 + (sr&31)) * IN_ + (kt) + swc*8; \
    const unsigned short* _g1 = Bm + (size_t)(n0 + 128 + (sr>>5)*64 + (h)*32 + (sr&31)) * IN_ + (kt) + swc*8; \
    unsigned short* _l = Bs_ + ((bb)*2 + (h))*8192 + sr*64 + sc*8; \
    gload_lds16(_g0, _l); \
    gload_lds16(_g1, _l + 4096); \
} while (0)

#define READ_A(bb, qm) do { \
    const unsigned short* _Ab = As_ + ((bb)*2 + (qm))*8192; \
    _Pragma("unroll") \
    for (int i = 0; i < 4; ++i) { \
        int rr = (arow + i*16) * 64; \
        a_[i][0] = *reinterpret_cast<const bf16x8*>(_Ab + rr + sl0); \
        a_[i][1] = *reinterpret_cast<const bf16x8*>(_Ab + rr + sl1); \
    } \
} while (0)

#define READ_B(bb, qn) do { \
    const unsigned short* _Bb = Bs_ + ((bb)*2 + (qn))*8192; \
    _Pragma("unroll") \
    for (int j = 0; j < 2; ++j) { \
        int rr = (brow + j*16) * 64; \
        b_[j][0] = *reinterpret_cast<const bf16x8*>(_Bb + rr + sl0); \
        b_[j][1] = *reinterpret_cast<const bf16x8*>(_Bb + rr + sl1); \
    } \
} while (0)

#define MFMA4(qm, qn) \
    _Pragma("unroll") \
    for (int i = 0; i < 4; ++i) { \
        _Pragma("unroll") \
        for (int j = 0; j < 2; ++j) { \
            acc[(qm)*4+i][(qn)*2+j] = __builtin_amdgcn_mfma_f32_16x16x32_bf16( \
                a_[i][0], b_[j][0], acc[(qm)*4+i][(qn)*2+j], 0, 0, 0); \
            acc[(qm)*4+i][(qn)*2+j] = __builtin_amdgcn_mfma_f32_16x16x32_bf16( \
                a_[i][1], b_[j][1], acc[(qm)*4+i][(qn)*2+j], 0, 0, 0); \
        } \
    }

#define LGKM0 do { \
    asm volatile("s_waitcnt lgkmcnt(0)" ::: "memory"); \
    __builtin_amdgcn_sched_barrier(0); \
} while (0)

#define VMN(n) do { \
    asm volatile("s_waitcnt vmcnt(" #n ")" ::: "memory"); \
    __builtin_amdgcn_sched_barrier(0); \
} while (0)

#define SP(p, ktn) do { \
    AU_LOAD(avX, 0);                        /* u0 */ \
    STAGE_B((p)^1, 0, ktn); \
    STAGE_B((p)^1, 1, ktn); \
    READ_B(p, 0); READ_A(p, 0); \
    LGKM0; \
    __builtin_amdgcn_s_setprio(1); \
    MFMA4(0, 0) \
    __builtin_amdgcn_s_setprio(0); \
    AU_LOAD(avY, 1);                        /* u1 */ \
    READ_B(p, 1); \
    LGKM0; \
    __builtin_amdgcn_s_setprio(1); \
    MFMA4(0, 1) \
    __builtin_amdgcn_s_setprio(0); \
    VMN(12);                                /* u0 landed (~2 bursts) */ \
    AU_CW(avX, 0, (p)^1); \
    AU_LOAD(avX, 2);                        /* u2 (reuse regs) */ \
    READ_A(p, 1); \
    LGKM0; \
    __builtin_amdgcn_s_setprio(1); \
    MFMA4(1, 1) \
    __builtin_amdgcn_s_setprio(0); \
    VMN(8);                                 /* B + u1 landed */ \
    AU_CW(avY, 1, (p)^1); \
    AU_LOAD(avY, 3);                        /* u3 (reuse regs) */ \
    READ_B(p, 0); \
    LGKM0; \
    __builtin_amdgcn_s_setprio(1); \
    MFMA4(1, 0) \
    __builtin_amdgcn_s_setprio(0); \
    VMN(0);                                 /* u2,u3 landed */ \
    AU_CW(avX, 2, (p)^1); \
    AU_CW(avY, 3, (p)^1); \
    asm volatile("s_waitcnt lgkmcnt(0)" ::: "memory"); \
    __builtin_amdgcn_s_barrier(); \
} while (0)

    f32x4 acc[8][4] = {};
    bf16x8 a_[4][2], b_[2][2];
    float avX[8], avY[8];

    // Prologue: stage K-tile 0 -> buf0 (A via AU units, B via gload_lds).
    {
        const float* ab2 = ABASE(0);
        AU_LOAD(avX, 0); AU_LOAD(avY, 1);
        STAGE_B(0, 0, 0); STAGE_B(0, 1, 0);
        VMN(12); AU_CW(avX, 0, 0); AU_LOAD(avX, 2);
        VMN(8);  AU_CW(avY, 1, 0); AU_LOAD(avY, 3);
        VMN(0);  AU_CW(avX, 2, 0); AU_CW(avY, 3, 0);
        asm volatile("s_waitcnt lgkmcnt(0)" ::: "memory");
        __builtin_amdgcn_s_barrier();
    }

    // 32 K-tiles; SP(p=t&1) computes tile t, stages t+1. Last stage wraps to
    // kt=0 (dead: valid addresses, never consumed).
    for (int it = 0; it < IN_ / 128; ++it) {
        int ktA = it * 128 + 64;
        int ktB = (it * 128 + 128) & (IN_ - 1);
        { const float* ab2 = ABASE(ktA); SP(0, ktA); }
        { const float* ab2 = ABASE(ktB); SP(1, ktB); }
    }

    // Epilogue: bias + store. C/D layout: col = lane&15, row = (lane>>4)*4 + reg.
    float bv[4];
    #pragma unroll
    for (int n_ = 0; n_ < 4; ++n_) bv[n_] = bias[n0 + wn * 64 + n_ * 16 + fr];
    int crow0 = m0 + wm * 128 + (lane >> 4) * 4;
    int ccol0 = n0 + wn * 64 + fr;
    #pragma unroll
    for (int mi = 0; mi < 8; ++mi) {
        #pragma unroll
        for (int r_ = 0; r_ < 4; ++r_) {
            float* cp = C + (size_t)(crow0 + mi * 16 + r_) * OUT_ + ccol0;
            #pragma unroll
            for (int n_ = 0; n_ < 4; ++n_) cp[n_ * 16] = acc[mi][n_][r_] + bv[n_];
        }
    }
#undef ABASE
#undef AU_LOAD
#undef AU_CW
#undef STAGE_B
#undef READ_A
#undef READ_B
#undef MFMA4
#undef LGKM0
#undef VMN
#undef SP
}

// ---------------------------------------------------------------------------
// Fallback (only if workspace too small): naive fp32, correct but slow.
__global__ __launch_bounds__(256) void naive_kernel(
        const float* __restrict__ in1, const float* __restrict__ in2a,
        const float* __restrict__ in2b, const float* __restrict__ W,
        const float* __restrict__ bias, float* __restrict__ out) {
    size_t id = (size_t)blockIdx.x * 256 + threadIdx.x;
    int s = (int)(id & (S_ - 1));
    size_t bo = id >> 11;
    int o = (int)(bo & (OUT_ - 1));
    int b = (int)(bo >> 11);
    const float* w = W + (size_t)o * IN_;
    float acc = bias[o];
    const float* x1 = in1 + (size_t)b * D1_ * S_ + s;
    for (int f = 0; f < D1_; ++f) acc += x1[(size_t)f * S_] * w[f];
    const float* x2 = in2a + (size_t)b * DJ_ * S_ + s;
    for (int f = 0; f < DJ_; ++f) acc += x2[(size_t)f * S_] * w[D1_ + f];
    const float* x3 = in2b + (size_t)b * DJ_ * S_ + s;
    for (int f = 0; f < DJ_; ++f) acc += x3[(size_t)f * S_] * w[D1_ + DJ_ + f];
    out[((size_t)b * S_ + s) * OUT_ + o] = acc;
}

// ---------------------------------------------------------------------------
extern "C" void kernel_launch(void* const* d_in, const int* in_sizes, int n_in,
                              void* d_out, int out_size, void* d_ws, size_t ws_size,
                              hipStream_t stream) {
    const float* in1  = (const float*)d_in[0];
    const float* in2a = (const float*)d_in[1];
    const float* in2b = (const float*)d_in[2];
    const float* W    = (const float*)d_in[3];
    const float* bias = (const float*)d_in[4];
    float* out = (float*)d_out;

    const size_t wb_bytes = (size_t)OUT_ * IN_ * 2;    // 8,388,608

    if (ws_size < wb_bytes) {
        naive_kernel<<<(B_ * (size_t)OUT_ * S_) / 256, 256, 0, stream>>>(
            in1, in2a, in2b, W, bias, out);
        return;
    }

    unsigned short* Wb = (unsigned short*)d_ws;

    convert_w_kernel<<<(OUT_ * IN_) / (256 * 8), 256, 0, stream>>>(W, Wb);
    gemm256_kernel<<<(M_TOT / 256) * (OUT_ / 256), 512, 0, stream>>>(
        in1, in2a, in2b, Wb, bias, out);
}

// Round 11
// 165.380 us; speedup vs baseline: 1.3373x; 1.3373x over previous
//
#include <hip/hip_runtime.h>
#include <hip/hip_bf16.h>

// Problem constants
#define B_   8
#define D1_  1024
#define DJ_  512
#define S_   2048
#define OUT_ 2048
#define IN_  2048          // D1 + 2*DJ
#define M_TOT (B_ * S_)    // 16384

typedef __attribute__((ext_vector_type(8))) short          bf16x8;
typedef __attribute__((ext_vector_type(8))) unsigned short ushort8;
typedef __attribute__((ext_vector_type(4))) float          f32x4;

typedef __attribute__((address_space(3))) unsigned int as3_uint;
typedef __attribute__((address_space(1))) unsigned int as1_uint;

__device__ __forceinline__ unsigned short f2bf(float f) {
    union { float f; unsigned u; } v; v.f = f;
    unsigned r = v.u + 0x7FFF + ((v.u >> 16) & 1);   // round-to-nearest-even
    return (unsigned short)(r >> 16);
}

__device__ __forceinline__ void gload_lds16(const void* g, const void* l) {
    __builtin_amdgcn_global_load_lds(
        (const as1_uint*)(unsigned long long)g,
        (as3_uint*)(unsigned int)(unsigned long long)l,
        16, 0, 0);
}

// ---------------------------------------------------------------------------
// Kernel 1 (merged prep, == round 7): blocks [0,8192) = concat+transpose+cvt;
// blocks [8192,10240) = W f32->bf16.  Runs at ~memory roofline.
__global__ __launch_bounds__(256) void prep_kernel(
        const float* __restrict__ in1, const float* __restrict__ in2a,
        const float* __restrict__ in2b, const float* __restrict__ W,
        unsigned short* __restrict__ Xt, unsigned short* __restrict__ Wb) {
    int bid = blockIdx.x;
    if (bid >= 8192) {
        size_t i = (size_t)(bid - 8192) * 256 + threadIdx.x;
        const float4* p = reinterpret_cast<const float4*>(W) + i * 2;
        float4 a = p[0], c = p[1];
        ushort8 h;
        h[0] = f2bf(a.x); h[1] = f2bf(a.y); h[2] = f2bf(a.z); h[3] = f2bf(a.w);
        h[4] = f2bf(c.x); h[5] = f2bf(c.y); h[6] = f2bf(c.z); h[7] = f2bf(c.w);
        *(reinterpret_cast<ushort8*>(Wb) + i) = h;
        return;
    }
    __shared__ float tile[64][65];
    int st = bid & 31;
    int ft = (bid >> 5) & 31;
    int b  = bid >> 10;
    int f0 = ft << 6, s0 = st << 6;

    const float* src; int frel;
    if (f0 < D1_)             { src = in1  + (size_t)b * D1_ * S_; frel = f0; }
    else if (f0 < D1_ + DJ_)  { src = in2a + (size_t)b * DJ_ * S_; frel = f0 - D1_; }
    else                      { src = in2b + (size_t)b * DJ_ * S_; frel = f0 - (D1_ + DJ_); }

    int t = threadIdx.x;
    int tr = t >> 4, tc = t & 15;
    #pragma unroll
    for (int i = 0; i < 4; ++i) {
        int fi = tr + i * 16;
        const float4 v = *reinterpret_cast<const float4*>(
            &src[(size_t)(frel + fi) * S_ + s0 + tc * 4]);
        tile[fi][tc * 4 + 0] = v.x; tile[fi][tc * 4 + 1] = v.y;
        tile[fi][tc * 4 + 2] = v.z; tile[fi][tc * 4 + 3] = v.w;
    }
    __syncthreads();
    int si0 = t >> 3, fx = t & 7;
    #pragma unroll
    for (int i = 0; i < 2; ++i) {
        int si = si0 + i * 32;
        ushort8 h;
        #pragma unroll
        for (int j = 0; j < 8; ++j) h[j] = f2bf(tile[fx * 8 + j][si]);
        *reinterpret_cast<ushort8*>(
            &Xt[(size_t)(b * S_ + s0 + si) * IN_ + f0 + fx * 8]) = h;
    }
}

// ---------------------------------------------------------------------------
// Kernel 2: 256x256 bf16 GEMM, ONE barrier per K-tile + B double-set (rd 11).
// C[M,N] = A[M,K]*B[N,K]^T + bias.  512 thr = 8 waves (2M x 4N).
// LDS: As_/Bs_ [2 buf][2 region][128][64] bf16 = 128 KiB.  T2 swizzle both.
// Per SP(p, ktn): compute K-tile t from buf p; stage t+1 (ktn) -> p^1.
//   top:  8 gload_lds (A 4 + B 4) for t+1      [full-SP slack to the fence]
//   READ_B0 + READ_A0 (12 ds) ; lgkm0 ; q(0,0) burst (b0_)
//   READ_B1 (4 ds)            ; lgkm0 ; q(0,1) burst (b1_)
//   READ_A1 (8 ds)            ; lgkm0 ; q(1,1) (b1_) + q(1,0) (b0_) -- 32 MFMA
//   vmcnt(0) [drains this SP's stages, issued ~2000 cyc ago vs HBM ~900 - no
//   stall] ; barrier.
// LDS reads/wave/K-tile = 24 KB (floor: A panel + B panel each read once).
// WAR: stages write p^1; its last reads retired before the previous SP's
//   barrier (reads of p^1 all happen in SP(t-1) before its trailing barrier).
// RAW: reads of p drained by SP(t-1)'s vmcnt(0) + barrier.
// B-sets b0_/b1_: written in this SP (from buf p) before first use; next
//   overwrite is next SP, after the barrier that follows their last reader.

__global__ __launch_bounds__(512, 2) void gemm256_kernel(
        const unsigned short* __restrict__ A,    // Xt [M_TOT][IN_] bf16
        const unsigned short* __restrict__ Bm,   // Wb [OUT_][IN_] bf16
        const float* __restrict__ bias,
        float* __restrict__ C) {
    __shared__ unsigned short As_[32768];   // [2][2][128][64]
    __shared__ unsigned short Bs_[32768];

    int bid = blockIdx.x;
    // XCD swizzle: nwg = 512 = 8 * 64 (divisible -> simple form bijective)
    int swz = (bid & 7) * 64 + (bid >> 3);
    int m0 = (swz >> 3) * 256;
    int n0 = (swz & 7) * 256;

    int t = threadIdx.x;
    int lane = t & 63, wave = t >> 6;
    int wm = wave >> 2;
    int wn = wave & 3;
    int fr = lane & 15;
    int fkslot = lane >> 4;

    // staging constants
    int sr  = t >> 3;
    int sc  = t & 7;
    int swc = sc ^ (sr & 7);       // pre-swizzled global k-slot (involution)

    // ds_read swizzled slot offsets (elements) for kk=0,1
    int sl0 = ((fkslot)     ^ (fr & 7)) * 8;
    int sl1 = ((4 + fkslot) ^ (fr & 7)) * 8;
    int arow = wm * 64 + fr;
    int brow = wn * 32 + fr;

#define STAGE_A(bb, h, kt) do { \
    const unsigned short* _g0 = A + (size_t)(m0 + (h)*64 + sr) * IN_ + (kt) + swc*8; \
    const unsigned short* _g1 = A + (size_t)(m0 + 128 + (h)*64 + sr) * IN_ + (kt) + swc*8; \
    unsigned short* _l = As_ + ((bb)*2 + (h))*8192 + sr*64 + sc*8; \
    gload_lds16(_g0, _l); \
    gload_lds16(_g1, _l + 4096); \
} while (0)

#define STAGE_B(bb, h, kt) do { \
    const unsigned short* _g0 = Bm + (size_t)(n0 + (sr>>5)*64 + (h)*32 + (sr&31)) * IN_ + (kt) + swc*8; \
    const unsigned short* _g1 = Bm + (size_t)(n0 + 128 + (sr>>5)*64 + (h)*32 + (sr&31)) * IN_ + (kt) + swc*8; \
    unsigned short* _l = Bs_ + ((bb)*2 + (h))*8192 + sr*64 + sc*8; \
    gload_lds16(_g0, _l); \
    gload_lds16(_g1, _l + 4096); \
} while (0)

#define READ_A(bb, qm) do { \
    const unsigned short* _Ab = As_ + ((bb)*2 + (qm))*8192; \
    _Pragma("unroll") \
    for (int i = 0; i < 4; ++i) { \
        int rr = (arow + i*16) * 64; \
        a_[i][0] = *reinterpret_cast<const bf16x8*>(_Ab + rr + sl0); \
        a_[i][1] = *reinterpret_cast<const bf16x8*>(_Ab + rr + sl1); \
    } \
} while (0)

#define READ_B(bb, qn, DST) do { \
    const unsigned short* _Bb = Bs_ + ((bb)*2 + (qn))*8192; \
    _Pragma("unroll") \
    for (int j = 0; j < 2; ++j) { \
        int rr = (brow + j*16) * 64; \
        DST[j][0] = *reinterpret_cast<const bf16x8*>(_Bb + rr + sl0); \
        DST[j][1] = *reinterpret_cast<const bf16x8*>(_Bb + rr + sl1); \
    } \
} while (0)

#define MFMA4(qm, qn, BS) \
    _Pragma("unroll") \
    for (int i = 0; i < 4; ++i) { \
        _Pragma("unroll") \
        for (int j = 0; j < 2; ++j) { \
            acc[(qm)*4+i][(qn)*2+j] = __builtin_amdgcn_mfma_f32_16x16x32_bf16( \
                a_[i][0], BS[j][0], acc[(qm)*4+i][(qn)*2+j], 0, 0, 0); \
            acc[(qm)*4+i][(qn)*2+j] = __builtin_amdgcn_mfma_f32_16x16x32_bf16( \
                a_[i][1], BS[j][1], acc[(qm)*4+i][(qn)*2+j], 0, 0, 0); \
        } \
    }

#define LGKM0 do { \
    asm volatile("s_waitcnt lgkmcnt(0)" ::: "memory"); \
    __builtin_amdgcn_sched_barrier(0); \
} while (0)

// One K-tile, one barrier.
#define SP(p, ktn) do { \
    STAGE_A((p)^1, 0, ktn); \
    STAGE_A((p)^1, 1, ktn); \
    STAGE_B((p)^1, 0, ktn); \
    STAGE_B((p)^1, 1, ktn); \
    READ_B(p, 0, b0_); \
    READ_A(p, 0); \
    LGKM0; \
    __builtin_amdgcn_s_setprio(1); \
    MFMA4(0, 0, b0_) \
    __builtin_amdgcn_s_setprio(0); \
    READ_B(p, 1, b1_); \
    LGKM0; \
    __builtin_amdgcn_s_setprio(1); \
    MFMA4(0, 1, b1_) \
    __builtin_amdgcn_s_setprio(0); \
    READ_A(p, 1); \
    LGKM0; \
    __builtin_amdgcn_s_setprio(1); \
    MFMA4(1, 1, b1_) \
    MFMA4(1, 0, b0_) \
    __builtin_amdgcn_s_setprio(0); \
    asm volatile("s_waitcnt vmcnt(0)" ::: "memory"); \
    __builtin_amdgcn_s_barrier(); \
} while (0)

    f32x4 acc[8][4] = {};
    bf16x8 a_[4][2], b0_[2][2], b1_[2][2];

    // Prologue: stage K-tile 0 -> buf0.
    STAGE_A(0, 0, 0); STAGE_A(0, 1, 0);
    STAGE_B(0, 0, 0); STAGE_B(0, 1, 0);
    asm volatile("s_waitcnt vmcnt(0)" ::: "memory");
    __builtin_amdgcn_s_barrier();

    // 32 K-tiles; K-tile it lives in buf it&1.  Last stage wraps to kt=0
    // (dead: valid addresses, never consumed).
    for (int it = 0; it < IN_ / 128; ++it) {
        int k1 = it * 128 + 64;
        int k2 = (it * 128 + 128) & (IN_ - 1);
        SP(0, k1);
        SP(1, k2);
    }

    // Epilogue: bias + store. C/D layout: col = lane&15, row = (lane>>4)*4 + reg.
    float bv[4];
    #pragma unroll
    for (int n_ = 0; n_ < 4; ++n_) bv[n_] = bias[n0 + wn * 64 + n_ * 16 + fr];
    int crow0 = m0 + wm * 128 + (lane >> 4) * 4;
    int ccol0 = n0 + wn * 64 + fr;
    #pragma unroll
    for (int mi = 0; mi < 8; ++mi) {
        #pragma unroll
        for (int r_ = 0; r_ < 4; ++r_) {
            float* cp = C + (size_t)(crow0 + mi * 16 + r_) * OUT_ + ccol0;
            #pragma unroll
            for (int n_ = 0; n_ < 4; ++n_) cp[n_ * 16] = acc[mi][n_][r_] + bv[n_];
        }
    }
#undef STAGE_A
#undef STAGE_B
#undef READ_A
#undef READ_B
#undef MFMA4
#undef LGKM0
#undef SP
}

// ---------------------------------------------------------------------------
// Fallback (only if workspace too small): naive fp32, correct but slow.
__global__ __launch_bounds__(256) void naive_kernel(
        const float* __restrict__ in1, const float* __restrict__ in2a,
        const float* __restrict__ in2b, const float* __restrict__ W,
        const float* __restrict__ bias, float* __restrict__ out) {
    size_t id = (size_t)blockIdx.x * 256 + threadIdx.x;
    int s = (int)(id & (S_ - 1));
    size_t bo = id >> 11;
    int o = (int)(bo & (OUT_ - 1));
    int b = (int)(bo >> 11);
    const float* w = W + (size_t)o * IN_;
    float acc = bias[o];
    const float* x1 = in1 + (size_t)b * D1_ * S_ + s;
    for (int f = 0; f < D1_; ++f) acc += x1[(size_t)f * S_] * w[f];
    const float* x2 = in2a + (size_t)b * DJ_ * S_ + s;
    for (int f = 0; f < DJ_; ++f) acc += x2[(size_t)f * S_] * w[D1_ + f];
    const float* x3 = in2b + (size_t)b * DJ_ * S_ + s;
    for (int f = 0; f < DJ_; ++f) acc += x3[(size_t)f * S_] * w[D1_ + DJ_ + f];
    out[((size_t)b * S_ + s) * OUT_ + o] = acc;
}

// ---------------------------------------------------------------------------
extern "C" void kernel_launch(void* const* d_in, const int* in_sizes, int n_in,
                              void* d_out, int out_size, void* d_ws, size_t ws_size,
                              hipStream_t stream) {
    const float* in1  = (const float*)d_in[0];
    const float* in2a = (const float*)d_in[1];
    const float* in2b = (const float*)d_in[2];
    const float* W    = (const float*)d_in[3];
    const float* bias = (const float*)d_in[4];
    float* out = (float*)d_out;

    const size_t xt_bytes = (size_t)M_TOT * IN_ * 2;   // 67,108,864
    const size_t wb_bytes = (size_t)OUT_ * IN_ * 2;    //  8,388,608

    if (ws_size < xt_bytes + wb_bytes) {
        naive_kernel<<<(B_ * (size_t)OUT_ * S_) / 256, 256, 0, stream>>>(
            in1, in2a, in2b, W, bias, out);
        return;
    }

    unsigned short* Xt = (unsigned short*)d_ws;
    unsigned short* Wb = (unsigned short*)((char*)d_ws + xt_bytes);

    prep_kernel<<<8192 + (OUT_ * IN_) / (256 * 8), 256, 0, stream>>>(
        in1, in2a, in2b, W, Xt, Wb);
    gemm256_kernel<<<(M_TOT / 256) * (OUT_ / 256), 512, 0, stream>>>(Xt, Wb, bias, out);
}

// Round 12
// 160.185 us; speedup vs baseline: 1.3807x; 1.0324x over previous
//
#include <hip/hip_runtime.h>
#include <hip/hip_bf16.h>

// Problem constants
#define B_   8
#define D1_  1024
#define DJ_  512
#define S_   2048
#define OUT_ 2048
#define IN_  2048          // D1 + 2*DJ
#define M_TOT (B_ * S_)    // 16384

typedef __attribute__((ext_vector_type(8))) short          bf16x8;
typedef __attribute__((ext_vector_type(8))) unsigned short ushort8;
typedef __attribute__((ext_vector_type(4))) float          f32x4;

typedef __attribute__((address_space(3))) unsigned int as3_uint;
typedef __attribute__((address_space(1))) unsigned int as1_uint;

__device__ __forceinline__ unsigned short f2bf(float f) {
    union { float f; unsigned u; } v; v.f = f;
    unsigned r = v.u + 0x7FFF + ((v.u >> 16) & 1);   // round-to-nearest-even
    return (unsigned short)(r >> 16);
}

__device__ __forceinline__ void gload_lds16(const void* g, const void* l) {
    __builtin_amdgcn_global_load_lds(
        (const as1_uint*)(unsigned long long)g,
        (as3_uint*)(unsigned int)(unsigned long long)l,
        16, 0, 0);
}

// ---------------------------------------------------------------------------
// Kernel 1 (merged prep, == round 7): blocks [0,8192) = concat+transpose+cvt;
// blocks [8192,10240) = W f32->bf16.  Runs at ~memory roofline (~33us).
__global__ __launch_bounds__(256) void prep_kernel(
        const float* __restrict__ in1, const float* __restrict__ in2a,
        const float* __restrict__ in2b, const float* __restrict__ W,
        unsigned short* __restrict__ Xt, unsigned short* __restrict__ Wb) {
    int bid = blockIdx.x;
    if (bid >= 8192) {
        size_t i = (size_t)(bid - 8192) * 256 + threadIdx.x;
        const float4* p = reinterpret_cast<const float4*>(W) + i * 2;
        float4 a = p[0], c = p[1];
        ushort8 h;
        h[0] = f2bf(a.x); h[1] = f2bf(a.y); h[2] = f2bf(a.z); h[3] = f2bf(a.w);
        h[4] = f2bf(c.x); h[5] = f2bf(c.y); h[6] = f2bf(c.z); h[7] = f2bf(c.w);
        *(reinterpret_cast<ushort8*>(Wb) + i) = h;
        return;
    }
    __shared__ float tile[64][65];
    int st = bid & 31;
    int ft = (bid >> 5) & 31;
    int b  = bid >> 10;
    int f0 = ft << 6, s0 = st << 6;

    const float* src; int frel;
    if (f0 < D1_)             { src = in1  + (size_t)b * D1_ * S_; frel = f0; }
    else if (f0 < D1_ + DJ_)  { src = in2a + (size_t)b * DJ_ * S_; frel = f0 - D1_; }
    else                      { src = in2b + (size_t)b * DJ_ * S_; frel = f0 - (D1_ + DJ_); }

    int t = threadIdx.x;
    int tr = t >> 4, tc = t & 15;
    #pragma unroll
    for (int i = 0; i < 4; ++i) {
        int fi = tr + i * 16;
        const float4 v = *reinterpret_cast<const float4*>(
            &src[(size_t)(frel + fi) * S_ + s0 + tc * 4]);
        tile[fi][tc * 4 + 0] = v.x; tile[fi][tc * 4 + 1] = v.y;
        tile[fi][tc * 4 + 2] = v.z; tile[fi][tc * 4 + 3] = v.w;
    }
    __syncthreads();
    int si0 = t >> 3, fx = t & 7;
    #pragma unroll
    for (int i = 0; i < 2; ++i) {
        int si = si0 + i * 32;
        ushort8 h;
        #pragma unroll
        for (int j = 0; j < 8; ++j) h[j] = f2bf(tile[fx * 8 + j][si]);
        *reinterpret_cast<ushort8*>(
            &Xt[(size_t)(b * S_ + s0 + si) * IN_ + f0 + fx * 8]) = h;
    }
}

// ---------------------------------------------------------------------------
// Kernel 2: 256x256 bf16 GEMM (round 12) = round-7 skeleton (proven 125.7us)
// + B-fragment double-set (deletes the redundant 3rd READ_B per K-tile).
// C[M,N] = A[M,K]*B[N,K]^T + bias.  512 thr = 8 waves (2M x 4N).
// LDS: As_/Bs_ [2 buf][2 region][128][64] bf16 = 128 KiB.  T2 swizzle both.
// Stage ledger, k-offsets, vmcnt(4) fence positions (SP2/SP4 ends) and the
// prologue are IDENTICAL to round 7.  Only delta: b0_/b1_ named register sets
// persist across the SP pair (lifetimes: written in SP_EVEN, last read end of
// SP_ODD, rewritten next SP_EVEN -> >=1 barrier separation).  Per-wave LDS
// reads 28->24 KB/K-tile (the floor: each A/B element read exactly once).
// SP_ODD's 32 MFMAs run as one setprio burst (no mid-read -> no drain).

__global__ __launch_bounds__(512, 2) void gemm256_kernel(
        const unsigned short* __restrict__ A,    // Xt [M_TOT][IN_] bf16
        const unsigned short* __restrict__ Bm,   // Wb [OUT_][IN_] bf16
        const float* __restrict__ bias,
        float* __restrict__ C) {
    __shared__ unsigned short As_[32768];   // [2][2][128][64]
    __shared__ unsigned short Bs_[32768];

    int bid = blockIdx.x;
    // XCD swizzle: nwg = 512 = 8 * 64 (divisible -> simple form bijective)
    int swz = (bid & 7) * 64 + (bid >> 3);
    int m0 = (swz >> 3) * 256;
    int n0 = (swz & 7) * 256;

    int t = threadIdx.x;
    int lane = t & 63, wave = t >> 6;
    int wm = wave >> 2;
    int wn = wave & 3;
    int fr = lane & 15;
    int fkslot = lane >> 4;

    // staging constants
    int sr  = t >> 3;
    int sc  = t & 7;
    int swc = sc ^ (sr & 7);       // pre-swizzled global k-slot (involution)

    // ds_read swizzled slot offsets (elements) for kk=0,1
    int sl0 = ((fkslot)     ^ (fr & 7)) * 8;
    int sl1 = ((4 + fkslot) ^ (fr & 7)) * 8;
    int arow = wm * 64 + fr;
    int brow = wn * 32 + fr;

#define STAGE_A(bb, h, kt) do { \
    const unsigned short* _g0 = A + (size_t)(m0 + (h)*64 + sr) * IN_ + (kt) + swc*8; \
    const unsigned short* _g1 = A + (size_t)(m0 + 128 + (h)*64 + sr) * IN_ + (kt) + swc*8; \
    unsigned short* _l = As_ + ((bb)*2 + (h))*8192 + sr*64 + sc*8; \
    gload_lds16(_g0, _l); \
    gload_lds16(_g1, _l + 4096); \
} while (0)

#define STAGE_B(bb, h, kt) do { \
    const unsigned short* _g0 = Bm + (size_t)(n0 + (sr>>5)*64 + (h)*32 + (sr&31)) * IN_ + (kt) + swc*8; \
    const unsigned short* _g1 = Bm + (size_t)(n0 + 128 + (sr>>5)*64 + (h)*32 + (sr&31)) * IN_ + (kt) + swc*8; \
    unsigned short* _l = Bs_ + ((bb)*2 + (h))*8192 + sr*64 + sc*8; \
    gload_lds16(_g0, _l); \
    gload_lds16(_g1, _l + 4096); \
} while (0)

#define READ_A(bb, qm) do { \
    const unsigned short* _Ab = As_ + ((bb)*2 + (qm))*8192; \
    _Pragma("unroll") \
    for (int i = 0; i < 4; ++i) { \
        int rr = (arow + i*16) * 64; \
        a_[i][0] = *reinterpret_cast<const bf16x8*>(_Ab + rr + sl0); \
        a_[i][1] = *reinterpret_cast<const bf16x8*>(_Ab + rr + sl1); \
    } \
} while (0)

#define READ_B(bb, qn, DST) do { \
    const unsigned short* _Bb = Bs_ + ((bb)*2 + (qn))*8192; \
    _Pragma("unroll") \
    for (int j = 0; j < 2; ++j) { \
        int rr = (brow + j*16) * 64; \
        DST[j][0] = *reinterpret_cast<const bf16x8*>(_Bb + rr + sl0); \
        DST[j][1] = *reinterpret_cast<const bf16x8*>(_Bb + rr + sl1); \
    } \
} while (0)

#define MFMA4(qm, qn, BS) \
    _Pragma("unroll") \
    for (int i = 0; i < 4; ++i) { \
        _Pragma("unroll") \
        for (int j = 0; j < 2; ++j) { \
            acc[(qm)*4+i][(qn)*2+j] = __builtin_amdgcn_mfma_f32_16x16x32_bf16( \
                a_[i][0], BS[j][0], acc[(qm)*4+i][(qn)*2+j], 0, 0, 0); \
            acc[(qm)*4+i][(qn)*2+j] = __builtin_amdgcn_mfma_f32_16x16x32_bf16( \
                a_[i][1], BS[j][1], acc[(qm)*4+i][(qn)*2+j], 0, 0, 0); \
        } \
    }

#define LGKM0 do { \
    asm volatile("s_waitcnt lgkmcnt(0)" ::: "memory"); \
    __builtin_amdgcn_sched_barrier(0); \
} while (0)

#define VMW asm volatile("s_waitcnt vmcnt(4)" ::: "memory")

// Superphase EVEN: quadrants (0,0) then (0,1) of buffer bb.
#define SP_EVEN(bb, S1, S2, VM_STMT) do { \
    READ_B(bb, 0, b0_); \
    READ_A(bb, 0); \
    S1; S2; \
    LGKM0; \
    __builtin_amdgcn_s_setprio(1); \
    MFMA4(0, 0, b0_) \
    __builtin_amdgcn_s_setprio(0); \
    READ_B(bb, 1, b1_); \
    LGKM0; \
    __builtin_amdgcn_s_setprio(1); \
    MFMA4(0, 1, b1_) \
    __builtin_amdgcn_s_setprio(0); \
    VM_STMT; \
    __builtin_amdgcn_s_barrier(); \
} while (0)

// Superphase ODD: quadrants (1,1)+(1,0); b0_/b1_ carried in from SP_EVEN.
#define SP_ODD(bb, S1, S2, VM_STMT) do { \
    READ_A(bb, 1); \
    S1; S2; \
    LGKM0; \
    __builtin_amdgcn_s_setprio(1); \
    MFMA4(1, 1, b1_) \
    MFMA4(1, 0, b0_) \
    __builtin_amdgcn_s_setprio(0); \
    VM_STMT; \
    __builtin_amdgcn_s_barrier(); \
} while (0)

    f32x4 acc[8][4] = {};
    bf16x8 a_[4][2], b0_[2][2], b1_[2][2];

    // Prologue (identical to r7): buf0 full (8 loads), buf1.A0 + buf1.B1 (4).
    STAGE_A(0, 0, 0);  STAGE_A(0, 1, 0);
    STAGE_B(0, 0, 0);  STAGE_B(0, 1, 0);
    STAGE_A(1, 0, 64); STAGE_B(1, 1, 64);
    asm volatile("s_waitcnt vmcnt(4)" ::: "memory");   // buf0 fully landed
    __builtin_amdgcn_s_barrier();

    // Main loop: iter it computes K-tiles 2it (buf0, SP1-2) and 2it+1 (buf1, SP3-4).
    // Stage ledger (== r7):
    //  SP1: buf1.A1(2it+1), buf1.B0(2it+1)   SP2: buf0.A0(2it+2), buf0.B1(2it+2)
    //  SP3: buf0.A1(2it+2), buf0.B0(2it+2)   SP4: buf1.A0(2it+3), buf1.B1(2it+3)
    for (int it = 0; it < IN_ / 128; ++it) {
        int k1 = it * 128 + 64;
        int k2 = (it * 128 + 128) & (IN_ - 1);   // wrap: last-iter stages are dead
        int k3 = (it * 128 + 192) & (IN_ - 1);
        SP_EVEN(0, STAGE_A(1, 1, k1), STAGE_B(1, 0, k1), );     // SP1
        SP_ODD (0, STAGE_A(0, 0, k2), STAGE_B(0, 1, k2), VMW);  // SP2
        SP_EVEN(1, STAGE_A(0, 1, k2), STAGE_B(0, 0, k2), );     // SP3
        SP_ODD (1, STAGE_A(1, 0, k3), STAGE_B(1, 1, k3), VMW);  // SP4
    }

    // Epilogue: bias + store. C/D layout: col = lane&15, row = (lane>>4)*4 + reg.
    float bv[4];
    #pragma unroll
    for (int n_ = 0; n_ < 4; ++n_) bv[n_] = bias[n0 + wn * 64 + n_ * 16 + fr];
    int crow0 = m0 + wm * 128 + (lane >> 4) * 4;
    int ccol0 = n0 + wn * 64 + fr;
    #pragma unroll
    for (int mi = 0; mi < 8; ++mi) {
        #pragma unroll
        for (int r_ = 0; r_ < 4; ++r_) {
            float* cp = C + (size_t)(crow0 + mi * 16 + r_) * OUT_ + ccol0;
            #pragma unroll
            for (int n_ = 0; n_ < 4; ++n_) cp[n_ * 16] = acc[mi][n_][r_] + bv[n_];
        }
    }
#undef STAGE_A
#undef STAGE_B
#undef READ_A
#undef READ_B
#undef MFMA4
#undef LGKM0
#undef VMW
#undef SP_EVEN
#undef SP_ODD
}

// ---------------------------------------------------------------------------
// Fallback (only if workspace too small): naive fp32, correct but slow.
__global__ __launch_bounds__(256) void naive_kernel(
        const float* __restrict__ in1, const float* __restrict__ in2a,
        const float* __restrict__ in2b, const float* __restrict__ W,
        const float* __restrict__ bias, float* __restrict__ out) {
    size_t id = (size_t)blockIdx.x * 256 + threadIdx.x;
    int s = (int)(id & (S_ - 1));
    size_t bo = id >> 11;
    int o = (int)(bo & (OUT_ - 1));
    int b = (int)(bo >> 11);
    const float* w = W + (size_t)o * IN_;
    float acc = bias[o];
    const float* x1 = in1 + (size_t)b * D1_ * S_ + s;
    for (int f = 0; f < D1_; ++f) acc += x1[(size_t)f * S_] * w[f];
    const float* x2 = in2a + (size_t)b * DJ_ * S_ + s;
    for (int f = 0; f < DJ_; ++f) acc += x2[(size_t)f * S_] * w[D1_ + f];
    const float* x3 = in2b + (size_t)b * DJ_ * S_ + s;
    for (int f = 0; f < DJ_; ++f) acc += x3[(size_t)f * S_] * w[D1_ + DJ_ + f];
    out[((size_t)b * S_ + s) * OUT_ + o] = acc;
}

// ---------------------------------------------------------------------------
extern "C" void kernel_launch(void* const* d_in, const int* in_sizes, int n_in,
                              void* d_out, int out_size, void* d_ws, size_t ws_size,
                              hipStream_t stream) {
    const float* in1  = (const float*)d_in[0];
    const float* in2a = (const float*)d_in[1];
    const float* in2b = (const float*)d_in[2];
    const float* W    = (const float*)d_in[3];
    const float* bias = (const float*)d_in[4];
    float* out = (float*)d_out;

    const size_t xt_bytes = (size_t)M_TOT * IN_ * 2;   // 67,108,864
    const size_t wb_bytes = (size_t)OUT_ * IN_ * 2;    //  8,388,608

    if (ws_size < xt_bytes + wb_bytes) {
        naive_kernel<<<(B_ * (size_t)OUT_ * S_) / 256, 256, 0, stream>>>(
            in1, in2a, in2b, W, bias, out);
        return;
    }

    unsigned short* Xt = (unsigned short*)d_ws;
    unsigned short* Wb = (unsigned short*)((char*)d_ws + xt_bytes);

    prep_kernel<<<8192 + (OUT_ * IN_) / (256 * 8), 256, 0, stream>>>(
        in1, in2a, in2b, W, Xt, Wb);
    gemm256_kernel<<<(M_TOT / 256) * (OUT_ / 256), 512, 0, stream>>>(Xt, Wb, bias, out);
}